// Round 4
// baseline (307.600 us; speedup 1.0000x reference)
//
#include <hip/hip_runtime.h>

#define B_ROWS   16384
#define D_DIM    2048
#define L_LAYERS 6

#define ROW_THREADS 256                       // 4 waves/block
#define ROW_WAVES   (ROW_THREADS / 64)
#define ROW_BLOCKS  1024
#define TOTAL_WAVES (ROW_BLOCKS * ROW_WAVES)  // 4096 waves
#define ROWS_PER_WAVE (B_ROWS / TOTAL_WAVES)  // 4 rows per wave, pipelined
#define PRE_THREADS 1024
#define WS_FLOATS   (D_DIM + L_LAYERS)        // U[2048] + e[6]

static_assert(ROWS_PER_WAVE == 4, "pipeline below is hand-unrolled for 4");

typedef float f32x4 __attribute__((ext_vector_type(4)));

// Exact algebra: x_l = c_l*x0 + u_l, u_l = sum_{i<l} b_i,
//   c_{l+1} = c_l*(1 + x0.W_l) + u_l.W_l.
// Whole net = 6 dots/row + scalar recurrence + out = c*x0 + U.
//
// R5: R3 post-mortem showed occupancy was NOT the limit (18->37% occ,
// time flat 85->90us, VALUBusy 12%, BW 2.3TB/s = 45% of copy ceiling).
// The limit is per-wave latency structure: one-shot load burst -> long
// load-silent dot/shuffle stretch -> store -> exit. Fix = software
// pipelining: 4 rows/wave, double-buffered x prefetch (A/B, statically
// indexed to avoid scratch), so row i+1's HBM loads are in flight while
// row i computes. W stays in global (48KB, L2-resident). U in LDS (8KB).
// U/e precomputed once into d_ws by a 1-block kernel.

// ---- kernel A: U = sum_i b_i ; e[l] = (sum_{i<l} b_i) . W_l ----
__global__ __launch_bounds__(PRE_THREADS) void precompute_Ue(
    const float* __restrict__ W,
    const float* __restrict__ b,
    float* __restrict__ ws)
{
    __shared__ float red[PRE_THREADS / 64][L_LAYERS];
    const int t    = threadIdx.x;
    const int lane = t & 63;
    const int wid  = t >> 6;
    const int base = t * 2;                        // 1024 x 2 = 2048

    float2 prefix = make_float2(0.f, 0.f);
    float e_red[L_LAYERS];
    #pragma unroll
    for (int l = 0; l < L_LAYERS; ++l) {
        const float2 wv = *(const float2*)(W + l * D_DIM + base);
        const float2 bv = *(const float2*)(b + l * D_DIM + base);
        e_red[l] = prefix.x * wv.x + prefix.y * wv.y;   // prefix BEFORE b_l
        prefix.x += bv.x; prefix.y += bv.y;
    }
    *(float2*)(ws + base) = prefix;                // U
    #pragma unroll
    for (int l = 0; l < L_LAYERS; ++l) {
        float v = e_red[l];
        #pragma unroll
        for (int off = 32; off >= 1; off >>= 1) v += __shfl_xor(v, off, 64);
        if (lane == 0) red[wid][l] = v;
    }
    __syncthreads();
    if (t < L_LAYERS) {
        float s = 0.f;
        #pragma unroll
        for (int w = 0; w < PRE_THREADS / 64; ++w) s += red[w][t];
        ws[D_DIM + t] = s;                         // e[l]
    }
}

// ---- kernel B: 4 rows/wave, double-buffered prefetch ----
template <bool USE_WS>
__global__ __launch_bounds__(ROW_THREADS) void cross_rows(
    const float* __restrict__ x,
    const float* __restrict__ W,
    const float* __restrict__ b,
    const float* __restrict__ ws,
    float* __restrict__ out)
{
    __shared__ float Ul[D_DIM];                    // 8 KB
    __shared__ float eLs[L_LAYERS];
    __shared__ float red[ROW_WAVES][L_LAYERS];     // fallback only

    const int t    = threadIdx.x;
    const int lane = t & 63;
    const int wid  = t >> 6;

    if constexpr (USE_WS) {
        const int base = t * 8;                    // 256 x 8 = 2048
        *(float4*)&Ul[base]     = *(const float4*)(ws + base);
        *(float4*)&Ul[base + 4] = *(const float4*)(ws + base + 4);
        if (t < L_LAYERS) eLs[t] = ws[D_DIM + t];
        __syncthreads();
    } else {
        const int base = t * 8;
        float4 p0 = make_float4(0.f, 0.f, 0.f, 0.f);
        float4 p1 = make_float4(0.f, 0.f, 0.f, 0.f);
        float e_red[L_LAYERS];
        #pragma unroll
        for (int l = 0; l < L_LAYERS; ++l) {
            const float4 w0 = *(const float4*)(W + l * D_DIM + base);
            const float4 w1 = *(const float4*)(W + l * D_DIM + base + 4);
            const float4 b0 = *(const float4*)(b + l * D_DIM + base);
            const float4 b1 = *(const float4*)(b + l * D_DIM + base + 4);
            e_red[l] = p0.x * w0.x + p0.y * w0.y + p0.z * w0.z + p0.w * w0.w
                     + p1.x * w1.x + p1.y * w1.y + p1.z * w1.z + p1.w * w1.w;
            p0.x += b0.x; p0.y += b0.y; p0.z += b0.z; p0.w += b0.w;
            p1.x += b1.x; p1.y += b1.y; p1.z += b1.z; p1.w += b1.w;
        }
        *(float4*)&Ul[base]     = p0;
        *(float4*)&Ul[base + 4] = p1;
        #pragma unroll
        for (int l = 0; l < L_LAYERS; ++l) {
            float v = e_red[l];
            #pragma unroll
            for (int off = 32; off >= 1; off >>= 1) v += __shfl_xor(v, off, 64);
            if (lane == 0) red[wid][l] = v;
        }
        __syncthreads();
        if (t < L_LAYERS) {
            float s = 0.f;
            #pragma unroll
            for (int w = 0; w < ROW_WAVES; ++w) s += red[w][t];
            eLs[t] = s;
        }
        __syncthreads();
    }

    const int gw = blockIdx.x * ROW_WAVES + wid;
    const float* xr = x + (size_t)gw * ROWS_PER_WAVE * D_DIM;
    float* orow     = out + (size_t)gw * ROWS_PER_WAVE * D_DIM;
    const int eoff  = lane * 4;                    // + j*256, j=0..7

    float4 xA[8], xB[8];                           // double buffer (static idx)

    auto loadRow = [&](float4 (&xv)[8], const float* p) {
        #pragma unroll
        for (int j = 0; j < 8; ++j) xv[j] = *(const float4*)(p + j * 256 + eoff);
    };

    auto computeStore = [&](const float4 (&xv)[8], float* op) {
        float p[L_LAYERS];
        #pragma unroll
        for (int l = 0; l < L_LAYERS; ++l) {
            float a = 0.f;
            #pragma unroll
            for (int j = 0; j < 8; ++j) {
                const float4 wv = *(const float4*)(W + l * D_DIM + j * 256 + eoff);
                a += xv[j].x * wv.x + xv[j].y * wv.y
                   + xv[j].z * wv.z + xv[j].w * wv.w;
            }
            p[l] = a;
        }
        #pragma unroll
        for (int off = 32; off >= 1; off >>= 1) {
            #pragma unroll
            for (int l = 0; l < L_LAYERS; ++l)
                p[l] += __shfl_xor(p[l], off, 64);
        }
        float c = 1.f;
        #pragma unroll
        for (int l = 0; l < L_LAYERS; ++l)
            c = c * (1.f + p[l]) + eLs[l];
        #pragma unroll
        for (int j = 0; j < 8; ++j) {
            const float4 uv = *(const float4*)&Ul[j * 256 + eoff];
            f32x4 o;
            o.x = c * xv[j].x + uv.x; o.y = c * xv[j].y + uv.y;
            o.z = c * xv[j].z + uv.z; o.w = c * xv[j].w + uv.w;
            __builtin_nontemporal_store(o, (f32x4*)(op + j * 256 + eoff));
        }
    };

    // 4-row pipeline, depth 2: row i+1 loads in flight during row i compute
    loadRow(xA, xr);
    loadRow(xB, xr + D_DIM);
    computeStore(xA, orow);
    loadRow(xA, xr + 2 * (size_t)D_DIM);
    computeStore(xB, orow + D_DIM);
    loadRow(xB, xr + 3 * (size_t)D_DIM);
    computeStore(xA, orow + 2 * (size_t)D_DIM);
    computeStore(xB, orow + 3 * (size_t)D_DIM);
}

extern "C" void kernel_launch(void* const* d_in, const int* in_sizes, int n_in,
                              void* d_out, int out_size, void* d_ws, size_t ws_size,
                              hipStream_t stream) {
    (void)in_sizes; (void)n_in; (void)out_size;
    const float* x = (const float*)d_in[0];
    const float* W = (const float*)d_in[1];
    const float* b = (const float*)d_in[2];
    float* out = (float*)d_out;

    const bool use_ws = (d_ws != nullptr) && (ws_size >= WS_FLOATS * sizeof(float));
    if (use_ws) {
        float* ws = (float*)d_ws;
        precompute_Ue<<<dim3(1), dim3(PRE_THREADS), 0, stream>>>(W, b, ws);
        cross_rows<true><<<dim3(ROW_BLOCKS), dim3(ROW_THREADS), 0, stream>>>(
            x, W, b, ws, out);
    } else {
        cross_rows<false><<<dim3(ROW_BLOCKS), dim3(ROW_THREADS), 0, stream>>>(
            x, W, b, nullptr, out);
    }
}

// Round 5
// 264.536 us; speedup vs baseline: 1.1628x; 1.1628x over previous
//
#include <hip/hip_runtime.h>

#define B_ROWS   16384
#define D_DIM    2048
#define L_LAYERS 6

#define THREADS  512                          // 8 waves/block
#define WPB      (THREADS / 64)
#define ROWS_PER_WAVE 4
#define TOTAL_WAVES (B_ROWS / ROWS_PER_WAVE)  // 4096
#define BLOCKS   (TOTAL_WAVES / WPB)          // 512
#define PRE_THREADS 1024
#define WS_FLOATS   (D_DIM + L_LAYERS)        // U[2048] + e[6]

typedef float f32x4 __attribute__((ext_vector_type(4)));

// Exact algebra: x_l = c_l*x0 + u_l, u_l = sum_{i<l} b_i,
//   c_{l+1} = c_l*(1 + x0.W_l) + u_l.W_l.
// Whole net = 6 dots/row + scalar recurrence + out = c*x0 + U.
//
// R6: R4's pipeline died of register thrash (VGPR=256, scratch 198MB) --
// the idea was never tested. This version enforces the register budget:
//  - exactly TWO x buffers A/B (64 VGPR), statically indexed, 4 rows/wave.
//  - W in LDS: dot-phase reads are lgkmcnt, NOT vmcnt -> the vmcnt FIFO
//    holds only x loads + out stores, so buffer-reuse waits are partial
//    (vmcnt(8): older stores retired, younger still in flight), never a
//    full drain.
//  - schedule: dots(cur) -> store(cur) -> sched_barrier(0) -> prefetch.
//    The pin stops the compiler hoisting the prefetch (and its implicit
//    store-hazard wait) above the compute that hides it.
//  - __launch_bounds__(512,2): VGPR cap 128 (natural ~110; R2's spill
//    cliff was a 64 cap, far away).
//  - LDS 56.8KB -> 2 blocks/CU = 16 waves/CU.

// ---- kernel A: U = sum_i b_i ; e[l] = (sum_{i<l} b_i) . W_l ----
__global__ __launch_bounds__(PRE_THREADS) void precompute_Ue(
    const float* __restrict__ W,
    const float* __restrict__ b,
    float* __restrict__ ws)
{
    __shared__ float red[PRE_THREADS / 64][L_LAYERS];
    const int t    = threadIdx.x;
    const int lane = t & 63;
    const int wid  = t >> 6;
    const int base = t * 2;                        // 1024 x 2 = 2048

    float2 prefix = make_float2(0.f, 0.f);
    float e_red[L_LAYERS];
    #pragma unroll
    for (int l = 0; l < L_LAYERS; ++l) {
        const float2 wv = *(const float2*)(W + l * D_DIM + base);
        const float2 bv = *(const float2*)(b + l * D_DIM + base);
        e_red[l] = prefix.x * wv.x + prefix.y * wv.y;   // prefix BEFORE b_l
        prefix.x += bv.x; prefix.y += bv.y;
    }
    *(float2*)(ws + base) = prefix;                // U
    #pragma unroll
    for (int l = 0; l < L_LAYERS; ++l) {
        float v = e_red[l];
        #pragma unroll
        for (int off = 32; off >= 1; off >>= 1) v += __shfl_xor(v, off, 64);
        if (lane == 0) red[wid][l] = v;
    }
    __syncthreads();
    if (t < L_LAYERS) {
        float s = 0.f;
        #pragma unroll
        for (int w = 0; w < PRE_THREADS / 64; ++w) s += red[w][t];
        ws[D_DIM + t] = s;                         // e[l]
    }
}

// ---- kernel B: 4 rows/wave, A/B pipelined, W in LDS ----
template <bool USE_WS>
__global__ __launch_bounds__(THREADS, 2) void cross_rows(
    const float* __restrict__ x,
    const float* __restrict__ W,
    const float* __restrict__ b,
    const float* __restrict__ ws,
    float* __restrict__ out)
{
    __shared__ float Wl[L_LAYERS][D_DIM];          // 48 KB
    __shared__ float Ul[D_DIM];                    // 8 KB
    __shared__ float eLs[L_LAYERS];
    __shared__ float red[WPB][L_LAYERS];           // fallback only

    const int t    = threadIdx.x;
    const int lane = t & 63;
    const int wid  = t >> 6;
    const int gw   = blockIdx.x * WPB + wid;
    const float* xr = x + (size_t)gw * ROWS_PER_WAVE * D_DIM;
    float* orow     = out + (size_t)gw * ROWS_PER_WAVE * D_DIM;
    const int eoff  = lane * 4;                    // + j*256, j=0..7

    float4 A[8], B[8];                             // the ONLY x buffers

    // prefetch rows 0,1 first: HBM latency hides under staging + barrier
    #pragma unroll
    for (int j = 0; j < 8; ++j) A[j] = *(const float4*)(xr + j * 256 + eoff);
    #pragma unroll
    for (int j = 0; j < 8; ++j) B[j] = *(const float4*)(xr + D_DIM + j * 256 + eoff);

    // ---- stage W into LDS (512 thr x 4 floats x 6 layers) ----
    {
        const int base = t * 4;
        #pragma unroll
        for (int l = 0; l < L_LAYERS; ++l)
            *(float4*)&Wl[l][base] = *(const float4*)(W + l * D_DIM + base);
    }
    if constexpr (USE_WS) {
        const int base = t * 4;
        *(float4*)&Ul[base] = *(const float4*)(ws + base);
        if (t < L_LAYERS) eLs[t] = ws[D_DIM + t];
    } else {
        const int base = t * 4;
        float4 prefix = make_float4(0.f, 0.f, 0.f, 0.f);
        float e_red[L_LAYERS];
        #pragma unroll
        for (int l = 0; l < L_LAYERS; ++l) {
            const float4 wv = *(const float4*)(W + l * D_DIM + base);
            const float4 bv = *(const float4*)(b + l * D_DIM + base);
            e_red[l] = prefix.x * wv.x + prefix.y * wv.y
                     + prefix.z * wv.z + prefix.w * wv.w;  // prefix BEFORE b_l
            prefix.x += bv.x; prefix.y += bv.y;
            prefix.z += bv.z; prefix.w += bv.w;
        }
        *(float4*)&Ul[base] = prefix;
        #pragma unroll
        for (int l = 0; l < L_LAYERS; ++l) {
            float v = e_red[l];
            #pragma unroll
            for (int off = 32; off >= 1; off >>= 1) v += __shfl_xor(v, off, 64);
            if (lane == 0) red[wid][l] = v;
        }
        __syncthreads();
        if (t < L_LAYERS) {
            float s = 0.f;
            #pragma unroll
            for (int w = 0; w < WPB; ++w) s += red[w][t];
            eLs[t] = s;
        }
    }
    __syncthreads();

    // ---- helpers (static buffer refs only; no runtime indexing) ----
    auto loadRow = [&](float4 (&xv)[8], const float* p) {
        #pragma unroll
        for (int j = 0; j < 8; ++j) xv[j] = *(const float4*)(p + j * 256 + eoff);
    };

    auto dotsC = [&](const float4 (&xv)[8]) -> float {
        float p[L_LAYERS];
        #pragma unroll
        for (int l = 0; l < L_LAYERS; ++l) {
            float a = 0.f;
            #pragma unroll
            for (int j = 0; j < 8; ++j) {
                const float4 wv = *(const float4*)&Wl[l][j * 256 + eoff];
                a += xv[j].x * wv.x + xv[j].y * wv.y
                   + xv[j].z * wv.z + xv[j].w * wv.w;
            }
            p[l] = a;
        }
        #pragma unroll
        for (int off = 32; off >= 1; off >>= 1) {
            #pragma unroll
            for (int l = 0; l < L_LAYERS; ++l)
                p[l] += __shfl_xor(p[l], off, 64);
        }
        float c = 1.f;
        #pragma unroll
        for (int l = 0; l < L_LAYERS; ++l)
            c = c * (1.f + p[l]) + eLs[l];
        return c;
    };

    auto applyStore = [&](const float4 (&xv)[8], float c, float* op) {
        #pragma unroll
        for (int j = 0; j < 8; ++j) {
            const float4 uv = *(const float4*)&Ul[j * 256 + eoff];
            f32x4 o;
            o.x = c * xv[j].x + uv.x; o.y = c * xv[j].y + uv.y;
            o.z = c * xv[j].z + uv.z; o.w = c * xv[j].w + uv.w;
            __builtin_nontemporal_store(o, (f32x4*)(op + j * 256 + eoff));
        }
    };

    // ---- 4-row pipeline: loads for row i+2 issue while row i+1 computes ----
    // it0
    {
        const float c0 = dotsC(A);
        applyStore(A, c0, orow);
    }
    // it1
    {
        const float c1 = dotsC(B);
        applyStore(B, c1, orow + D_DIM);
        __builtin_amdgcn_sched_barrier(0);     // pin: prefetch stays here
        loadRow(A, xr + 2 * (size_t)D_DIM);    // waits only r0's stores (vmcnt partial)
    }
    // it2
    {
        const float c2 = dotsC(A);
        applyStore(A, c2, orow + 2 * (size_t)D_DIM);
        __builtin_amdgcn_sched_barrier(0);
        loadRow(B, xr + 3 * (size_t)D_DIM);
    }
    // it3
    {
        const float c3 = dotsC(B);
        applyStore(B, c3, orow + 3 * (size_t)D_DIM);
    }
}

extern "C" void kernel_launch(void* const* d_in, const int* in_sizes, int n_in,
                              void* d_out, int out_size, void* d_ws, size_t ws_size,
                              hipStream_t stream) {
    (void)in_sizes; (void)n_in; (void)out_size;
    const float* x = (const float*)d_in[0];
    const float* W = (const float*)d_in[1];
    const float* b = (const float*)d_in[2];
    float* out = (float*)d_out;

    const bool use_ws = (d_ws != nullptr) && (ws_size >= WS_FLOATS * sizeof(float));
    if (use_ws) {
        float* ws = (float*)d_ws;
        precompute_Ue<<<dim3(1), dim3(PRE_THREADS), 0, stream>>>(W, b, ws);
        cross_rows<true><<<dim3(BLOCKS), dim3(THREADS), 0, stream>>>(
            x, W, b, ws, out);
    } else {
        cross_rows<false><<<dim3(BLOCKS), dim3(THREADS), 0, stream>>>(
            x, W, b, nullptr, out);
    }
}

// Round 6
// 251.675 us; speedup vs baseline: 1.2222x; 1.0511x over previous
//
#include <hip/hip_runtime.h>

#define B_ROWS   16384
#define D_DIM    2048
#define L_LAYERS 6

#define THREADS  512                          // 8 waves/block
#define WPB      (THREADS / 64)
#define ROWS_PER_WAVE 4
#define TOTAL_WAVES (B_ROWS / ROWS_PER_WAVE)  // 4096
#define BLOCKS   (TOTAL_WAVES / WPB)          // 512
#define PRE_THREADS 1024
#define WS_FLOATS   (D_DIM + L_LAYERS)        // U[2048] + e[6]

typedef float f32x4 __attribute__((ext_vector_type(4)));

// Exact algebra: x_l = c_l*x0 + u_l, u_l = sum_{i<l} b_i,
//   c_{l+1} = c_l*(1 + x0.W_l) + u_l.W_l.
// Whole net = 6 dots/row + scalar recurrence + out = c*x0 + U.
//
// R7: every prior version kept x rows register-resident (32 VGPR/row),
// which (a) rides the spill cliff the moment anything else wants
// registers (R2: 315MB, R4: 198MB, R6: 188MB scratch traffic), and
// (b) forces a full vmcnt drain per row (dot needs the whole row; apply
// re-reads the same regs -> WAR). Fix: never retain x.
//  Phase A: stream x, FMA-on-arrival into 24 scalar accumulators, discard.
//           Loads issue continuously across all 4 rows of the wave.
//           W from LDS so the vmcnt FIFO holds ONLY x loads.
//  reduce:  one 64-lane butterfly per 4 rows (was: per row).
//  Phase B: re-read x (L2/L3-hot, x < 256MB L3 -> no extra HBM fetch),
//           out = c*x + U, nontemporal stores. Copy-shaped.
// #pragma unroll 2 on the j-loops bounds in-flight temps (R4 lesson:
// full unroll lets the allocator batch 300+ load dests -> spill).
// No launch_bounds VGPR cap (R6 lesson: cap 128 spilled); natural ~100.

// ---- kernel A: U = sum_i b_i ; e[l] = (sum_{i<l} b_i) . W_l ----
__global__ __launch_bounds__(PRE_THREADS) void precompute_Ue(
    const float* __restrict__ W,
    const float* __restrict__ b,
    float* __restrict__ ws)
{
    __shared__ float red[PRE_THREADS / 64][L_LAYERS];
    const int t    = threadIdx.x;
    const int lane = t & 63;
    const int wid  = t >> 6;
    const int base = t * 2;                        // 1024 x 2 = 2048

    float2 prefix = make_float2(0.f, 0.f);
    float e_red[L_LAYERS];
    #pragma unroll
    for (int l = 0; l < L_LAYERS; ++l) {
        const float2 wv = *(const float2*)(W + l * D_DIM + base);
        const float2 bv = *(const float2*)(b + l * D_DIM + base);
        e_red[l] = prefix.x * wv.x + prefix.y * wv.y;   // prefix BEFORE b_l
        prefix.x += bv.x; prefix.y += bv.y;
    }
    *(float2*)(ws + base) = prefix;                // U
    #pragma unroll
    for (int l = 0; l < L_LAYERS; ++l) {
        float v = e_red[l];
        #pragma unroll
        for (int off = 32; off >= 1; off >>= 1) v += __shfl_xor(v, off, 64);
        if (lane == 0) red[wid][l] = v;
    }
    __syncthreads();
    if (t < L_LAYERS) {
        float s = 0.f;
        #pragma unroll
        for (int w = 0; w < PRE_THREADS / 64; ++w) s += red[w][t];
        ws[D_DIM + t] = s;                         // e[l]
    }
}

// ---- kernel B: 4 rows/wave, stream-dot then stream-apply ----
template <bool USE_WS>
__global__ __launch_bounds__(THREADS) void cross_rows(
    const float* __restrict__ x,
    const float* __restrict__ W,
    const float* __restrict__ b,
    const float* __restrict__ ws,
    float* __restrict__ out)
{
    __shared__ float Wl[L_LAYERS][D_DIM];          // 48 KB
    __shared__ float Ul[D_DIM];                    // 8 KB
    __shared__ float eLs[L_LAYERS];
    __shared__ float red[WPB][L_LAYERS];           // fallback only

    const int t    = threadIdx.x;
    const int lane = t & 63;
    const int wid  = t >> 6;
    const int sbase = t * 4;                       // 512 x 4 = 2048

    // ---- stage W into LDS; U/e from ws (or fallback recompute) ----
    #pragma unroll
    for (int l = 0; l < L_LAYERS; ++l)
        *(float4*)&Wl[l][sbase] = *(const float4*)(W + l * D_DIM + sbase);
    if constexpr (USE_WS) {
        *(float4*)&Ul[sbase] = *(const float4*)(ws + sbase);
        if (t < L_LAYERS) eLs[t] = ws[D_DIM + t];
    } else {
        float4 prefix = make_float4(0.f, 0.f, 0.f, 0.f);
        float e_red[L_LAYERS];
        #pragma unroll
        for (int l = 0; l < L_LAYERS; ++l) {
            const float4 wv = *(const float4*)(W + l * D_DIM + sbase);
            const float4 bv = *(const float4*)(b + l * D_DIM + sbase);
            e_red[l] = prefix.x * wv.x + prefix.y * wv.y
                     + prefix.z * wv.z + prefix.w * wv.w;  // prefix BEFORE b_l
            prefix.x += bv.x; prefix.y += bv.y;
            prefix.z += bv.z; prefix.w += bv.w;
        }
        *(float4*)&Ul[sbase] = prefix;
        #pragma unroll
        for (int l = 0; l < L_LAYERS; ++l) {
            float v = e_red[l];
            #pragma unroll
            for (int off = 32; off >= 1; off >>= 1) v += __shfl_xor(v, off, 64);
            if (lane == 0) red[wid][l] = v;
        }
        __syncthreads();
        if (t < L_LAYERS) {
            float s = 0.f;
            #pragma unroll
            for (int w = 0; w < WPB; ++w) s += red[w][t];
            eLs[t] = s;
        }
    }
    __syncthreads();

    const int gw = blockIdx.x * WPB + wid;
    const float* xr = x + (size_t)gw * ROWS_PER_WAVE * D_DIM;
    float* orow     = out + (size_t)gw * ROWS_PER_WAVE * D_DIM;
    const int eoff  = lane * 4;                    // + j*256, j=0..7

    // ---- Phase A: streaming dots; x is consumed on arrival, not kept ----
    float p[ROWS_PER_WAVE][L_LAYERS];              // 24 accumulators
    #pragma unroll
    for (int r = 0; r < ROWS_PER_WAVE; ++r)
        #pragma unroll
        for (int l = 0; l < L_LAYERS; ++l) p[r][l] = 0.f;

    #pragma unroll 2
    for (int j = 0; j < 8; ++j) {
        float4 wv[L_LAYERS];
        #pragma unroll
        for (int l = 0; l < L_LAYERS; ++l)
            wv[l] = *(const float4*)&Wl[l][j * 256 + eoff];
        #pragma unroll
        for (int r = 0; r < ROWS_PER_WAVE; ++r) {
            const float4 xv = *(const float4*)(xr + (size_t)r * D_DIM + j * 256 + eoff);
            #pragma unroll
            for (int l = 0; l < L_LAYERS; ++l)
                p[r][l] += xv.x * wv[l].x + xv.y * wv[l].y
                         + xv.z * wv[l].z + xv.w * wv[l].w;
        }
    }

    // ---- one butterfly reduce per 4 rows ----
    #pragma unroll
    for (int off = 32; off >= 1; off >>= 1) {
        #pragma unroll
        for (int r = 0; r < ROWS_PER_WAVE; ++r)
            #pragma unroll
            for (int l = 0; l < L_LAYERS; ++l)
                p[r][l] += __shfl_xor(p[r][l], off, 64);
    }

    float c[ROWS_PER_WAVE];
    #pragma unroll
    for (int r = 0; r < ROWS_PER_WAVE; ++r) {
        float cr = 1.f;
        #pragma unroll
        for (int l = 0; l < L_LAYERS; ++l)
            cr = cr * (1.f + p[r][l]) + eLs[l];
        c[r] = cr;
    }

    // ---- Phase B: apply-stream; x re-read is L2/L3-hot (just touched) ----
    #pragma unroll 2
    for (int j = 0; j < 8; ++j) {
        const float4 uv = *(const float4*)&Ul[j * 256 + eoff];
        #pragma unroll
        for (int r = 0; r < ROWS_PER_WAVE; ++r) {
            const size_t off = (size_t)r * D_DIM + j * 256 + eoff;
            const float4 xv = *(const float4*)(xr + off);
            f32x4 o;
            o.x = c[r] * xv.x + uv.x; o.y = c[r] * xv.y + uv.y;
            o.z = c[r] * xv.z + uv.z; o.w = c[r] * xv.w + uv.w;
            __builtin_nontemporal_store(o, (f32x4*)(orow + off));
        }
    }
}

extern "C" void kernel_launch(void* const* d_in, const int* in_sizes, int n_in,
                              void* d_out, int out_size, void* d_ws, size_t ws_size,
                              hipStream_t stream) {
    (void)in_sizes; (void)n_in; (void)out_size;
    const float* x = (const float*)d_in[0];
    const float* W = (const float*)d_in[1];
    const float* b = (const float*)d_in[2];
    float* out = (float*)d_out;

    const bool use_ws = (d_ws != nullptr) && (ws_size >= WS_FLOATS * sizeof(float));
    if (use_ws) {
        float* ws = (float*)d_ws;
        precompute_Ue<<<dim3(1), dim3(PRE_THREADS), 0, stream>>>(W, b, ws);
        cross_rows<true><<<dim3(BLOCKS), dim3(THREADS), 0, stream>>>(
            x, W, b, ws, out);
    } else {
        cross_rows<false><<<dim3(BLOCKS), dim3(THREADS), 0, stream>>>(
            x, W, b, nullptr, out);
    }
}